// Round 11
// baseline (220.223 us; speedup 1.0000x reference)
//
#include <hip/hip_runtime.h>
#include <hip/hip_bf16.h>
#include <cstdint>
#include <cstddef>

// YatAttention on MI355X (gfx950).
// B=2, L=2048, E=768, H=12, D=64. GEMMs in bf16 MFMA 16x16x32 (fp32 accum).
// R13: attack the non-attn 118us. (1) gemm_core -> LDS double-buffer with ONE
// barrier per K-step (k_attn's proven pattern: issue glds(t+1) -> MFMA(t) ->
// barrier; was stage/barrier/compute/barrier with zero overlap). (2) qsq/ksq
// fused into k_gemm_qkv epilogue (lane owns d=ni*16+r16 at fixed row -> 
// partial sum + 4 shfl_xor over r16; values re-rounded via bf16 to keep
// numerics identical). (3) mbias moved to k_prep; k_prep2 DELETED -> 4
// dispatches, -12.6MB Q/K re-read. k_attn unchanged from R12 (93us pinned).

typedef __bf16 bf16_t;
typedef __bf16 bf16x8 __attribute__((ext_vector_type(8)));
typedef __bf16 bf16x4 __attribute__((ext_vector_type(4)));
typedef float floatx4 __attribute__((ext_vector_type(4)));

#define DEVI static __device__ __forceinline__

#define Bc 2
#define Lc 2048
#define Ec 768
#define Hc 12
#define Dc 64
#define N3c 2304
#define Mc 4096
#define ROWSc (Bc * Hc * Lc)  // 49152

DEVI void glds16(const bf16_t* g, bf16_t* l) {
  __builtin_amdgcn_global_load_lds(
      (const __attribute__((address_space(1))) void*)g,
      (__attribute__((address_space(3))) void*)l, 16, 0, 0);
}

// ---- fused prep: fp32->bf16 cvt + weight transposes + mask bias ----
// blocks [0,3072): cvt x; [3072,4800): Wqkv^T; [4800,5376): Wout^T;
// [5376,5392): mbias from mask.
__global__ __launch_bounds__(256) void k_prep(
    const float* __restrict__ x, bf16_t* __restrict__ xb,
    const float* __restrict__ Wqkv, bf16_t* __restrict__ WqT,
    const float* __restrict__ Wout, bf16_t* __restrict__ WoT,
    const int* __restrict__ mask, float* __restrict__ mbias) {
  __shared__ float tile[32][33];
  const int bid = blockIdx.x, tid = threadIdx.x;
  if (bid < 3072) {
    const int i = (bid * 256 + tid) * 4;
    float4 v = *(const float4*)(x + i);
    bf16x4 o;
    o[0] = (bf16_t)v.x; o[1] = (bf16_t)v.y; o[2] = (bf16_t)v.z; o[3] = (bf16_t)v.w;
    *(bf16x4*)(xb + i) = o;
    return;
  }
  if (bid >= 5376) {
    const int i = (bid - 5376) * 256 + tid;  // 0..4095
    mbias[i] = (mask[i] == 1) ? 0.f : -1e30f;
    return;
  }
  const float* in; bf16_t* out; int C, local;
  if (bid < 4800) { local = bid - 3072; in = Wqkv; out = WqT; C = N3c; }
  else            { local = bid - 4800; in = Wout; out = WoT; C = Ec;  }
  const int R = Ec;
  const int nbx = C / 32;
  const int c0 = (local % nbx) * 32, r0 = (local / nbx) * 32;
  const int tx = tid & 31, ty = tid >> 5;
  #pragma unroll
  for (int i = 0; i < 32; i += 8)
    tile[ty + i][tx] = in[(size_t)(r0 + ty + i) * C + c0 + tx];
  __syncthreads();
  #pragma unroll
  for (int i = 0; i < 32; i += 8)
    out[(size_t)(c0 + ty + i) * R + r0 + tx] = (bf16_t)tile[tx][ty + i];
}

// ---- GEMM core: BK=32, LDS double-buffer, ONE barrier per K-step ----
// Per iter: issue glds for tile t+1 (other buffer) -> MFMA tile t -> barrier
// (drains vmcnt: t+1 landed; latency hidden under MFMA). k_attn-proven.
DEVI void gemm_core(const bf16_t* __restrict__ A, const bf16_t* __restrict__ Bt,
                    bf16_t* lA, bf16_t* lB, int m0, int n0, floatx4 (&acc)[4][4]) {
  const int tid = threadIdx.x, wave = tid >> 6, lane = tid & 63;
  const int wm = (wave >> 1) * 64, wn = (wave & 1) * 64;
  const int lrow = lane >> 2, lseg = lane & 3;
  const int quad = lane >> 4, r16 = lane & 15;
  const bf16_t* a0 = A + (size_t)(m0 + wave * 32 + lrow) * 768 + lseg * 8;
  const bf16_t* a1 = A + (size_t)(m0 + wave * 32 + 16 + lrow) * 768 + lseg * 8;
  const bf16_t* b0 = Bt + (size_t)(n0 + wave * 32 + lrow) * 768 + lseg * 8;
  const bf16_t* b1 = Bt + (size_t)(n0 + wave * 32 + 16 + lrow) * 768 + lseg * 8;
  const int la0 = (wave * 32) * 32, la1 = (wave * 32 + 16) * 32;
  // prologue: tile 0 -> buf 0
  glds16(a0, lA + la0); glds16(a1, lA + la1);
  glds16(b0, lB + la0); glds16(b1, lB + la1);
  __syncthreads();
  for (int kk = 0; kk < 768; kk += 32) {
    const int cur = (kk >> 5) & 1;
    if (kk + 32 < 768) {
      const int nb = (cur ^ 1) * 4096;
      glds16(a0 + kk + 32, lA + nb + la0); glds16(a1 + kk + 32, lA + nb + la1);
      glds16(b0 + kk + 32, lB + nb + la0); glds16(b1 + kk + 32, lB + nb + la1);
    }
    const bf16_t* lac = lA + cur * 4096;
    const bf16_t* lbc = lB + cur * 4096;
    bf16x8 af[4], bv[4];
    #pragma unroll
    for (int mi = 0; mi < 4; mi++)
      af[mi] = *(const bf16x8*)(lac + (wm + mi * 16 + r16) * 32 + quad * 8);
    #pragma unroll
    for (int ni = 0; ni < 4; ni++)
      bv[ni] = *(const bf16x8*)(lbc + (wn + ni * 16 + r16) * 32 + quad * 8);
    #pragma unroll
    for (int mi = 0; mi < 4; mi++)
      #pragma unroll
      for (int ni = 0; ni < 4; ni++)
        acc[mi][ni] = __builtin_amdgcn_mfma_f32_16x16x32_bf16(af[mi], bv[ni], acc[mi][ni], 0, 0, 0);
    __syncthreads();
  }
}

// QKV GEMM. Q/K sections also emit qsq/ksq (fused row-sum-of-squares);
// V section (sec==2) writes VT[bh][d][l] directly (bf16x4 along l).
__global__ __launch_bounds__(256) void k_gemm_qkv(
    const bf16_t* __restrict__ A, const bf16_t* __restrict__ Bt,
    const float* __restrict__ bias,
    bf16_t* __restrict__ Qo, bf16_t* __restrict__ Ko, bf16_t* __restrict__ VTo,
    float* __restrict__ qsq, float* __restrict__ ksq) {
  __shared__ bf16_t lA[2 * 128 * 32];
  __shared__ bf16_t lB[2 * 128 * 32];
  const int m0 = blockIdx.y * 128, n0 = blockIdx.x * 128;
  const int tid = threadIdx.x, wave = tid >> 6, lane = tid & 63;
  const int wm = (wave >> 1) * 64, wn = (wave & 1) * 64;
  const int quad = lane >> 4, r16 = lane & 15;
  floatx4 acc[4][4] = {};
  gemm_core(A, Bt, lA, lB, m0, n0, acc);

  const int sec = n0 / 768;
  if (sec < 2) {
    bf16_t* dst = (sec == 0) ? Qo : Ko;
    float* sqo = (sec == 0) ? qsq : ksq;
    const float epsadd = (sec == 0) ? 0.f : 1e-6f;
    const int h = ((n0 + wn) - sec * 768) >> 6;  // one head per wave half
    float part[4][4];
    #pragma unroll
    for (int mi = 0; mi < 4; mi++)
      #pragma unroll
      for (int reg = 0; reg < 4; reg++) part[mi][reg] = 0.f;
    #pragma unroll
    for (int ni = 0; ni < 4; ni++) {
      const int n = n0 + wn + ni * 16 + r16;
      const int d = (n - sec * 768) & 63;
      const float bvs = bias[n];
      #pragma unroll
      for (int mi = 0; mi < 4; mi++) {
        #pragma unroll
        for (int reg = 0; reg < 4; reg++) {
          const int m = m0 + wm + mi * 16 + quad * 4 + reg;
          const int b = m >> 11, l = m & 2047;
          const bf16_t v = (bf16_t)(acc[mi][ni][reg] + bvs);
          dst[(((size_t)(b * Hc + h)) * Lc + l) * Dc + d] = v;
          const float vr = (float)v;  // bf16-rounded, matches old k_sq numerics
          part[mi][reg] += vr * vr;
        }
      }
    }
    // reduce over r16 (d dimension): masks 1,2,4,8 stay within quad group
    #pragma unroll
    for (int mi = 0; mi < 4; mi++) {
      #pragma unroll
      for (int reg = 0; reg < 4; reg++) {
        float s = part[mi][reg];
        s += __shfl_xor(s, 1);
        s += __shfl_xor(s, 2);
        s += __shfl_xor(s, 4);
        s += __shfl_xor(s, 8);
        if (r16 == 0) {
          const int m = m0 + wm + mi * 16 + quad * 4 + reg;
          const int b = m >> 11, l = m & 2047;
          sqo[(size_t)(b * Hc + h) * Lc + l] = s + epsadd;
        }
      }
    }
  } else {
    // V -> VT direct: lane owns fixed (h,d); regs are 4 consecutive l.
    #pragma unroll
    for (int ni = 0; ni < 4; ni++) {
      const int n = n0 + wn + ni * 16 + r16;
      const int nn = n - 1536;
      const int h = nn >> 6, d = nn & 63;
      const float bvs = bias[n];
      #pragma unroll
      for (int mi = 0; mi < 4; mi++) {
        const int m = m0 + wm + mi * 16 + quad * 4;
        const int b = m >> 11, l = m & 2047;
        bf16x4 o;
        #pragma unroll
        for (int reg = 0; reg < 4; reg++)
          o[reg] = (bf16_t)(acc[mi][ni][reg] + bvs);
        *(bf16x4*)(VTo + (((size_t)(b * Hc + h)) * Dc + d) * Lc + l) = o;
      }
    }
  }
}

__global__ __launch_bounds__(256) void k_gemm_out(
    const bf16_t* __restrict__ A, const bf16_t* __restrict__ Bt,
    const float* __restrict__ bias, float* __restrict__ out) {
  __shared__ bf16_t lA[2 * 128 * 32];
  __shared__ bf16_t lB[2 * 128 * 32];
  const int m0 = blockIdx.y * 128, n0 = blockIdx.x * 128;
  const int tid = threadIdx.x, wave = tid >> 6, lane = tid & 63;
  const int wm = (wave >> 1) * 64, wn = (wave & 1) * 64;
  const int quad = lane >> 4, r16 = lane & 15;
  floatx4 acc[4][4] = {};
  gemm_core(A, Bt, lA, lB, m0, n0, acc);
  #pragma unroll
  for (int ni = 0; ni < 4; ni++) {
    const int n = n0 + wn + ni * 16 + r16;
    const float bvs = bias[n];
    #pragma unroll
    for (int mi = 0; mi < 4; mi++) {
      #pragma unroll
      for (int reg = 0; reg < 4; reg++) {
        const int m = m0 + wm + mi * 16 + quad * 4 + reg;
        out[(size_t)m * Ec + n] = acc[mi][ni][reg] + bvs;
      }
    }
  }
}

// ---------------- flash attention: R12 k_attn (unchanged, ~93us) ----------
__global__ __launch_bounds__(256) void k_attn(
    const bf16_t* __restrict__ Q, const bf16_t* __restrict__ K,
    const bf16_t* __restrict__ VT, const float* __restrict__ qsq,
    const float* __restrict__ ksq, const float* __restrict__ mbias,
    bf16_t* __restrict__ AO) {
  __shared__ bf16_t lK[2][4096];    // 64 keys x 64 d, swizzled 16B chunks
  __shared__ bf16_t lV[2][4096];    // 64 d x 64 keys, swizzled 16B chunks
  __shared__ bf16_t lP[4][16 * 64]; // per-wave P, stride 64, chunk-XOR swizzle
  const int gid0 = blockIdx.x;
  const int gid = (gid0 & 7) * 96 + (gid0 >> 3);  // XCD swizzle: 3 bh per XCD
  const int bh = gid >> 5, qt = gid & 31;
  const int b = bh / Hc;
  const int h = bh - b * Hc;
  const int tid = threadIdx.x, wave = tid >> 6, lane = tid & 63;
  const int quad = lane >> 4, r16 = lane & 15;
  const int q0 = qt * 64 + wave * 16;
  const bf16_t* Qh = Q + ((size_t)bh * Lc) * Dc;
  const bf16_t* Kh = K + ((size_t)bh * Lc) * Dc;
  const bf16_t* VTh = VT + ((size_t)bh * Dc) * Lc;
  const float* qsqh = qsq + bh * Lc;
  const float* ksqh = ksq + bh * Lc;
  const float* mbb = mbias + b * Lc;
  bf16_t* myP = &lP[wave][0];

  const int p0 = wave * 64 + lane;
  const int srow = p0 >> 3;
  const int sj = (p0 & 7) ^ (srow & 7);
  const bf16_t* kg0 = Kh + (size_t)srow * 64 + sj * 8;
  const bf16_t* kg1 = kg0 + 32 * 64;
  const bf16_t* vg0 = VTh + (size_t)srow * Lc + sj * 8;
  const bf16_t* vg1 = vg0 + 32 * Lc;
  const int ld0 = wave * 64 * 8, ld1 = (256 + wave * 64) * 8;  // elements

  const int sl0 = ((quad ^ (r16 & 7)) * 8);
  const int sl1 = sl0 ^ 32;
  const int pswz = r16 & 7;

  bf16x8 qf0 = *(const bf16x8*)(Qh + (size_t)(q0 + r16) * 64 + quad * 8);
  bf16x8 qf1 = *(const bf16x8*)(Qh + (size_t)(q0 + r16) * 64 + 32 + quad * 8);
  const float qs = qsqh[q0 + r16];
  float mi = -1e30f;        // LOG2 domain, shared across the query's 4 lanes
  float li = 0.f;           // per-lane partial; reduced in epilogue
  floatx4 of[4] = {};

  glds16(kg0, &lK[0][ld0]);
  glds16(kg1, &lK[0][ld1]);
  glds16(vg0, &lV[0][ld0]);
  glds16(vg1, &lV[0][ld1]);
  kg0 += 4096; kg1 += 4096; vg0 += 64; vg1 += 64;
  float4 ks4[4], mb4[4];
  #pragma unroll
  for (int c = 0; c < 4; c++) {
    float4 kv = *(const float4*)(ksqh + c * 16 + quad * 4);
    ks4[c] = make_float4(kv.x + qs, kv.y + qs, kv.z + qs, kv.w + qs);
    mb4[c] = *(const float4*)(mbb + c * 16 + quad * 4);
  }
  __syncthreads();

  const int nt = Lc / 64;  // 32
  for (int t = 0; t < nt; t++) {
    const int cur = t & 1;
    const bool more = (t + 1 < nt);
    if (more) {
      const int nxt = cur ^ 1;
      glds16(kg0, &lK[nxt][ld0]);
      glds16(kg1, &lK[nxt][ld1]);
      glds16(vg0, &lV[nxt][ld0]);
      glds16(vg1, &lV[nxt][ld1]);
      kg0 += 4096; kg1 += 4096; vg0 += 64; vg1 += 64;
    }
    float4 ks4n[4], mb4n[4];
    if (more) {
      const int ktn = (t + 1) * 64;
      #pragma unroll
      for (int c = 0; c < 4; c++) {
        ks4n[c] = *(const float4*)(ksqh + ktn + c * 16 + quad * 4);
        mb4n[c] = *(const float4*)(mbb + ktn + c * 16 + quad * 4);
      }
    }
    floatx4 dot[4];
    __builtin_amdgcn_s_setprio(1);
    #pragma unroll
    for (int c = 0; c < 4; c++) {
      const int rbase = (c * 16 + r16) * 64;
      bf16x8 kf0 = *(const bf16x8*)(&lK[cur][rbase + sl0]);
      bf16x8 kf1 = *(const bf16x8*)(&lK[cur][rbase + sl1]);
      floatx4 a = {};
      a = __builtin_amdgcn_mfma_f32_16x16x32_bf16(kf0, qf0, a, 0, 0, 0);
      a = __builtin_amdgcn_mfma_f32_16x16x32_bf16(kf1, qf1, a, 0, 0, 0);
      dot[c] = a;
    }
    __builtin_amdgcn_s_setprio(0);
    float rmax = -1e30f;
    #pragma unroll
    for (int c = 0; c < 4; c++) {
      #pragma unroll
      for (int reg = 0; reg < 4; reg++) {
        const float dd = dot[c][reg];
        const float qks = ((const float*)&ks4[c])[reg];  // qs + kss + eps
        const float mbv = ((const float*)&mb4[c])[reg];
        const float den = __builtin_fmaf(dd, -2.f, qks);
        const float sc = __builtin_fmaf((dd * 1.44269504f) * dd,
                                        __builtin_amdgcn_rcpf(den), mbv);
        dot[c][reg] = sc;
        rmax = fmaxf(rmax, sc);
      }
    }
    if (!__all(rmax <= mi + 11.5416f)) {
      float rg = fmaxf(rmax, __shfl_xor(rmax, 16));
      rg = fmaxf(rg, __shfl_xor(rg, 32));
      const float mnew = fmaxf(mi, rg);
      const float alpha = exp2f(mi - mnew);
      li *= alpha;
      #pragma unroll
      for (int t4 = 0; t4 < 4; t4++) {
        #pragma unroll
        for (int reg = 0; reg < 4; reg++) of[t4][reg] *= alpha;
      }
      mi = mnew;
    }
    float psum = 0.f;
    #pragma unroll
    for (int c = 0; c < 4; c++) {
      bf16x4 pk;
      #pragma unroll
      for (int reg = 0; reg < 4; reg++) {
        const float p = exp2f(dot[c][reg] - mi);  // masked: exp2(-huge)=0
        psum += p;
        pk[reg] = (bf16_t)p;
      }
      const int jw = (2 * c + (quad >> 1)) ^ pswz;
      *(bf16x4*)(myP + r16 * 64 + jw * 8 + (quad & 1) * 4) = pk;
    }
    li += psum;
    bf16x8 pf0 = *(const bf16x8*)(myP + r16 * 64 + (quad ^ pswz) * 8);
    bf16x8 pf1 = *(const bf16x8*)(myP + r16 * 64 + ((4 + quad) ^ pswz) * 8);
    __builtin_amdgcn_s_setprio(1);
    #pragma unroll
    for (int t4 = 0; t4 < 4; t4++) {
      const int rbase = (t4 * 16 + r16) * 64;
      bf16x8 vf0 = *(const bf16x8*)(&lV[cur][rbase + sl0]);
      bf16x8 vf1 = *(const bf16x8*)(&lV[cur][rbase + sl1]);
      of[t4] = __builtin_amdgcn_mfma_f32_16x16x32_bf16(vf0, pf0, of[t4], 0, 0, 0);
      of[t4] = __builtin_amdgcn_mfma_f32_16x16x32_bf16(vf1, pf1, of[t4], 0, 0, 0);
    }
    __builtin_amdgcn_s_setprio(0);
    if (more) {
      #pragma unroll
      for (int c = 0; c < 4; c++) {
        ks4[c] = make_float4(ks4n[c].x + qs, ks4n[c].y + qs,
                             ks4n[c].z + qs, ks4n[c].w + qs);
        mb4[c] = mb4n[c];
      }
    }
    __syncthreads();
  }
  li += __shfl_xor(li, 16);
  li += __shfl_xor(li, 32);
  const float inv = (li > 0.f) ? __builtin_amdgcn_rcpf(li) : 0.f;
  bf16_t* aor = AO + ((size_t)(b * Lc + q0 + r16)) * Ec + h * 64;
  #pragma unroll
  for (int t4 = 0; t4 < 4; t4++) {
    bf16x4 o;
    #pragma unroll
    for (int reg = 0; reg < 4; reg++) o[reg] = (bf16_t)(of[t4][reg] * inv);
    *(bf16x4*)(aor + t4 * 16 + quad * 4) = o;
  }
}

// ---------------- launch ----------------

extern "C" void kernel_launch(void* const* d_in, const int* in_sizes, int n_in,
                              void* d_out, int out_size, void* d_ws, size_t ws_size,
                              hipStream_t stream) {
  const float* x    = (const float*)d_in[0];
  const int*   mask = (const int*)d_in[1];
  const float* Wqkv = (const float*)d_in[2];
  const float* bqkv = (const float*)d_in[3];
  const float* Wout = (const float*)d_in[4];
  const float* bout = (const float*)d_in[5];
  float* out = (float*)d_out;

  auto al = [](size_t x) { return (x + 255) & ~(size_t)255; };
  char* ws = (char*)d_ws;
  size_t off = 0;
  auto carve = [&](size_t bytes) -> char* {
    char* p = ws + off;
    off += al(bytes);
    return p;
  };
  bf16_t* WoT = (bf16_t*)carve((size_t)Ec * Ec * 2);
  bf16_t* Qb  = (bf16_t*)carve((size_t)ROWSc * Dc * 2);
  bf16_t* Kb  = (bf16_t*)carve((size_t)ROWSc * Dc * 2);
  bf16_t* VTb = (bf16_t*)carve((size_t)ROWSc * Dc * 2);
  bf16_t* AOb = (bf16_t*)carve((size_t)Mc * Ec * 2);
  float*  qsq = (float*)carve((size_t)ROWSc * 4);
  float*  ksq = (float*)carve((size_t)ROWSc * 4);
  float*  mbias = (float*)carve((size_t)Bc * Lc * 4);
  const size_t uni = off;
  bf16_t* xb  = (bf16_t*)(ws + uni);
  bf16_t* WqT = (bf16_t*)(ws + uni + al((size_t)Mc * Ec * 2));
  (void)in_sizes; (void)n_in; (void)out_size; (void)ws_size;

  k_prep<<<5392, 256, 0, stream>>>(x, xb, Wqkv, WqT, Wout, WoT, mask, mbias);
  k_gemm_qkv<<<dim3(N3c / 128, Mc / 128), 256, 0, stream>>>(xb, WqT, bqkv, Qb, Kb, VTb, qsq, ksq);
  k_attn<<<dim3(ROWSc / 64), 256, 0, stream>>>(Qb, Kb, VTb, qsq, ksq, mbias, AOb);
  k_gemm_out<<<dim3(Ec / 128, Mc / 128), 256, 0, stream>>>(AOb, WoT, bout, out);
}

// Round 12
// 218.404 us; speedup vs baseline: 1.0083x; 1.0083x over previous
//
#include <hip/hip_runtime.h>
#include <hip/hip_bf16.h>
#include <cstdint>
#include <cstddef>

// YatAttention on MI355X (gfx950).
// B=2, L=2048, E=768, H=12, D=64. GEMMs in bf16 MFMA 16x16x32 (fp32 accum).
// R14: un-bundle R13. gemm_core REVERTED to the proven single-buffer BK=32
// 2-barrier core (R13's dbuf doubled GEMM LDS 16->32KB and re-learned
// m99/m100: explicit dbuf at HIP source is neutral-to-negative). KEPT from
// R13: qsq/ksq fused into k_gemm_qkv epilogue, V->VT direct store, mbias in
// k_prep, k_prep2 deleted (4 dispatches). k_attn unchanged (~93us pinned).

typedef __bf16 bf16_t;
typedef __bf16 bf16x8 __attribute__((ext_vector_type(8)));
typedef __bf16 bf16x4 __attribute__((ext_vector_type(4)));
typedef float floatx4 __attribute__((ext_vector_type(4)));

#define DEVI static __device__ __forceinline__

#define Bc 2
#define Lc 2048
#define Ec 768
#define Hc 12
#define Dc 64
#define N3c 2304
#define Mc 4096
#define ROWSc (Bc * Hc * Lc)  // 49152

DEVI void glds16(const bf16_t* g, bf16_t* l) {
  __builtin_amdgcn_global_load_lds(
      (const __attribute__((address_space(1))) void*)g,
      (__attribute__((address_space(3))) void*)l, 16, 0, 0);
}

// ---- fused prep: fp32->bf16 cvt + weight transposes + mask bias ----
// blocks [0,3072): cvt x; [3072,4800): Wqkv^T; [4800,5376): Wout^T;
// [5376,5392): mbias from mask.
__global__ __launch_bounds__(256) void k_prep(
    const float* __restrict__ x, bf16_t* __restrict__ xb,
    const float* __restrict__ Wqkv, bf16_t* __restrict__ WqT,
    const float* __restrict__ Wout, bf16_t* __restrict__ WoT,
    const int* __restrict__ mask, float* __restrict__ mbias) {
  __shared__ float tile[32][33];
  const int bid = blockIdx.x, tid = threadIdx.x;
  if (bid < 3072) {
    const int i = (bid * 256 + tid) * 4;
    float4 v = *(const float4*)(x + i);
    bf16x4 o;
    o[0] = (bf16_t)v.x; o[1] = (bf16_t)v.y; o[2] = (bf16_t)v.z; o[3] = (bf16_t)v.w;
    *(bf16x4*)(xb + i) = o;
    return;
  }
  if (bid >= 5376) {
    const int i = (bid - 5376) * 256 + tid;  // 0..4095
    mbias[i] = (mask[i] == 1) ? 0.f : -1e30f;
    return;
  }
  const float* in; bf16_t* out; int C, local;
  if (bid < 4800) { local = bid - 3072; in = Wqkv; out = WqT; C = N3c; }
  else            { local = bid - 4800; in = Wout; out = WoT; C = Ec;  }
  const int R = Ec;
  const int nbx = C / 32;
  const int c0 = (local % nbx) * 32, r0 = (local / nbx) * 32;
  const int tx = tid & 31, ty = tid >> 5;
  #pragma unroll
  for (int i = 0; i < 32; i += 8)
    tile[ty + i][tx] = in[(size_t)(r0 + ty + i) * C + c0 + tx];
  __syncthreads();
  #pragma unroll
  for (int i = 0; i < 32; i += 8)
    out[(size_t)(c0 + ty + i) * R + r0 + tx] = (bf16_t)tile[tx][ty + i];
}

// ---------------- GEMM core (m97 pattern, BK=32 -- proven) ----------------

DEVI void gemm_core(const bf16_t* __restrict__ A, const bf16_t* __restrict__ Bt,
                    bf16_t* lA, bf16_t* lB, int m0, int n0, floatx4 (&acc)[4][4]) {
  const int tid = threadIdx.x, wave = tid >> 6, lane = tid & 63;
  const int wm = (wave >> 1) * 64, wn = (wave & 1) * 64;
  const int lrow = lane >> 2, lseg = lane & 3;
  const int quad = lane >> 4, r16 = lane & 15;
  for (int kk = 0; kk < 768; kk += 32) {
    glds16(A  + (size_t)(m0 + wave * 32      + lrow) * 768 + kk + lseg * 8, lA + (wave * 32) * 32);
    glds16(A  + (size_t)(m0 + wave * 32 + 16 + lrow) * 768 + kk + lseg * 8, lA + (wave * 32 + 16) * 32);
    glds16(Bt + (size_t)(n0 + wave * 32      + lrow) * 768 + kk + lseg * 8, lB + (wave * 32) * 32);
    glds16(Bt + (size_t)(n0 + wave * 32 + 16 + lrow) * 768 + kk + lseg * 8, lB + (wave * 32 + 16) * 32);
    __syncthreads();
    bf16x8 af[4], bv[4];
    #pragma unroll
    for (int mi = 0; mi < 4; mi++)
      af[mi] = *(const bf16x8*)(lA + (wm + mi * 16 + r16) * 32 + quad * 8);
    #pragma unroll
    for (int ni = 0; ni < 4; ni++)
      bv[ni] = *(const bf16x8*)(lB + (wn + ni * 16 + r16) * 32 + quad * 8);
    #pragma unroll
    for (int mi = 0; mi < 4; mi++)
      #pragma unroll
      for (int ni = 0; ni < 4; ni++)
        acc[mi][ni] = __builtin_amdgcn_mfma_f32_16x16x32_bf16(af[mi], bv[ni], acc[mi][ni], 0, 0, 0);
    __syncthreads();
  }
}

// QKV GEMM. Q/K sections also emit qsq/ksq (fused row-sum-of-squares);
// V section (sec==2) writes VT[bh][d][l] directly (bf16x4 along l).
__global__ __launch_bounds__(256) void k_gemm_qkv(
    const bf16_t* __restrict__ A, const bf16_t* __restrict__ Bt,
    const float* __restrict__ bias,
    bf16_t* __restrict__ Qo, bf16_t* __restrict__ Ko, bf16_t* __restrict__ VTo,
    float* __restrict__ qsq, float* __restrict__ ksq) {
  __shared__ bf16_t lA[128 * 32];
  __shared__ bf16_t lB[128 * 32];
  const int m0 = blockIdx.y * 128, n0 = blockIdx.x * 128;
  const int tid = threadIdx.x, wave = tid >> 6, lane = tid & 63;
  const int wm = (wave >> 1) * 64, wn = (wave & 1) * 64;
  const int quad = lane >> 4, r16 = lane & 15;
  floatx4 acc[4][4] = {};
  gemm_core(A, Bt, lA, lB, m0, n0, acc);

  const int sec = n0 / 768;
  if (sec < 2) {
    bf16_t* dst = (sec == 0) ? Qo : Ko;
    float* sqo = (sec == 0) ? qsq : ksq;
    const float epsadd = (sec == 0) ? 0.f : 1e-6f;
    const int h = ((n0 + wn) - sec * 768) >> 6;  // one head per wave half
    float part[4][4];
    #pragma unroll
    for (int mi = 0; mi < 4; mi++)
      #pragma unroll
      for (int reg = 0; reg < 4; reg++) part[mi][reg] = 0.f;
    #pragma unroll
    for (int ni = 0; ni < 4; ni++) {
      const int n = n0 + wn + ni * 16 + r16;
      const int d = (n - sec * 768) & 63;
      const float bvs = bias[n];
      #pragma unroll
      for (int mi = 0; mi < 4; mi++) {
        #pragma unroll
        for (int reg = 0; reg < 4; reg++) {
          const int m = m0 + wm + mi * 16 + quad * 4 + reg;
          const int b = m >> 11, l = m & 2047;
          const bf16_t v = (bf16_t)(acc[mi][ni][reg] + bvs);
          dst[(((size_t)(b * Hc + h)) * Lc + l) * Dc + d] = v;
          const float vr = (float)v;  // bf16-rounded, matches old k_sq numerics
          part[mi][reg] += vr * vr;
        }
      }
    }
    // reduce over r16 (d dimension): masks 1,2,4,8 stay within quad group
    #pragma unroll
    for (int mi = 0; mi < 4; mi++) {
      #pragma unroll
      for (int reg = 0; reg < 4; reg++) {
        float s = part[mi][reg];
        s += __shfl_xor(s, 1);
        s += __shfl_xor(s, 2);
        s += __shfl_xor(s, 4);
        s += __shfl_xor(s, 8);
        if (r16 == 0) {
          const int m = m0 + wm + mi * 16 + quad * 4 + reg;
          const int b = m >> 11, l = m & 2047;
          sqo[(size_t)(b * Hc + h) * Lc + l] = s + epsadd;
        }
      }
    }
  } else {
    // V -> VT direct: lane owns fixed (h,d); regs are 4 consecutive l.
    #pragma unroll
    for (int ni = 0; ni < 4; ni++) {
      const int n = n0 + wn + ni * 16 + r16;
      const int nn = n - 1536;
      const int h = nn >> 6, d = nn & 63;
      const float bvs = bias[n];
      #pragma unroll
      for (int mi = 0; mi < 4; mi++) {
        const int m = m0 + wm + mi * 16 + quad * 4;
        const int b = m >> 11, l = m & 2047;
        bf16x4 o;
        #pragma unroll
        for (int reg = 0; reg < 4; reg++)
          o[reg] = (bf16_t)(acc[mi][ni][reg] + bvs);
        *(bf16x4*)(VTo + (((size_t)(b * Hc + h)) * Dc + d) * Lc + l) = o;
      }
    }
  }
}

__global__ __launch_bounds__(256) void k_gemm_out(
    const bf16_t* __restrict__ A, const bf16_t* __restrict__ Bt,
    const float* __restrict__ bias, float* __restrict__ out) {
  __shared__ bf16_t lA[128 * 32];
  __shared__ bf16_t lB[128 * 32];
  const int m0 = blockIdx.y * 128, n0 = blockIdx.x * 128;
  const int tid = threadIdx.x, wave = tid >> 6, lane = tid & 63;
  const int wm = (wave >> 1) * 64, wn = (wave & 1) * 64;
  const int quad = lane >> 4, r16 = lane & 15;
  floatx4 acc[4][4] = {};
  gemm_core(A, Bt, lA, lB, m0, n0, acc);
  #pragma unroll
  for (int ni = 0; ni < 4; ni++) {
    const int n = n0 + wn + ni * 16 + r16;
    const float bvs = bias[n];
    #pragma unroll
    for (int mi = 0; mi < 4; mi++) {
      #pragma unroll
      for (int reg = 0; reg < 4; reg++) {
        const int m = m0 + wm + mi * 16 + quad * 4 + reg;
        out[(size_t)m * Ec + n] = acc[mi][ni][reg] + bvs;
      }
    }
  }
}

// ---------------- flash attention: R12 k_attn (unchanged, ~93us) ----------
__global__ __launch_bounds__(256) void k_attn(
    const bf16_t* __restrict__ Q, const bf16_t* __restrict__ K,
    const bf16_t* __restrict__ VT, const float* __restrict__ qsq,
    const float* __restrict__ ksq, const float* __restrict__ mbias,
    bf16_t* __restrict__ AO) {
  __shared__ bf16_t lK[2][4096];    // 64 keys x 64 d, swizzled 16B chunks
  __shared__ bf16_t lV[2][4096];    // 64 d x 64 keys, swizzled 16B chunks
  __shared__ bf16_t lP[4][16 * 64]; // per-wave P, stride 64, chunk-XOR swizzle
  const int gid0 = blockIdx.x;
  const int gid = (gid0 & 7) * 96 + (gid0 >> 3);  // XCD swizzle: 3 bh per XCD
  const int bh = gid >> 5, qt = gid & 31;
  const int b = bh / Hc;
  const int h = bh - b * Hc;
  const int tid = threadIdx.x, wave = tid >> 6, lane = tid & 63;
  const int quad = lane >> 4, r16 = lane & 15;
  const int q0 = qt * 64 + wave * 16;
  const bf16_t* Qh = Q + ((size_t)bh * Lc) * Dc;
  const bf16_t* Kh = K + ((size_t)bh * Lc) * Dc;
  const bf16_t* VTh = VT + ((size_t)bh * Dc) * Lc;
  const float* qsqh = qsq + bh * Lc;
  const float* ksqh = ksq + bh * Lc;
  const float* mbb = mbias + b * Lc;
  bf16_t* myP = &lP[wave][0];

  const int p0 = wave * 64 + lane;
  const int srow = p0 >> 3;
  const int sj = (p0 & 7) ^ (srow & 7);
  const bf16_t* kg0 = Kh + (size_t)srow * 64 + sj * 8;
  const bf16_t* kg1 = kg0 + 32 * 64;
  const bf16_t* vg0 = VTh + (size_t)srow * Lc + sj * 8;
  const bf16_t* vg1 = vg0 + 32 * Lc;
  const int ld0 = wave * 64 * 8, ld1 = (256 + wave * 64) * 8;  // elements

  const int sl0 = ((quad ^ (r16 & 7)) * 8);
  const int sl1 = sl0 ^ 32;
  const int pswz = r16 & 7;

  bf16x8 qf0 = *(const bf16x8*)(Qh + (size_t)(q0 + r16) * 64 + quad * 8);
  bf16x8 qf1 = *(const bf16x8*)(Qh + (size_t)(q0 + r16) * 64 + 32 + quad * 8);
  const float qs = qsqh[q0 + r16];
  float mi = -1e30f;        // LOG2 domain, shared across the query's 4 lanes
  float li = 0.f;           // per-lane partial; reduced in epilogue
  floatx4 of[4] = {};

  glds16(kg0, &lK[0][ld0]);
  glds16(kg1, &lK[0][ld1]);
  glds16(vg0, &lV[0][ld0]);
  glds16(vg1, &lV[0][ld1]);
  kg0 += 4096; kg1 += 4096; vg0 += 64; vg1 += 64;
  float4 ks4[4], mb4[4];
  #pragma unroll
  for (int c = 0; c < 4; c++) {
    float4 kv = *(const float4*)(ksqh + c * 16 + quad * 4);
    ks4[c] = make_float4(kv.x + qs, kv.y + qs, kv.z + qs, kv.w + qs);
    mb4[c] = *(const float4*)(mbb + c * 16 + quad * 4);
  }
  __syncthreads();

  const int nt = Lc / 64;  // 32
  for (int t = 0; t < nt; t++) {
    const int cur = t & 1;
    const bool more = (t + 1 < nt);
    if (more) {
      const int nxt = cur ^ 1;
      glds16(kg0, &lK[nxt][ld0]);
      glds16(kg1, &lK[nxt][ld1]);
      glds16(vg0, &lV[nxt][ld0]);
      glds16(vg1, &lV[nxt][ld1]);
      kg0 += 4096; kg1 += 4096; vg0 += 64; vg1 += 64;
    }
    float4 ks4n[4], mb4n[4];
    if (more) {
      const int ktn = (t + 1) * 64;
      #pragma unroll
      for (int c = 0; c < 4; c++) {
        ks4n[c] = *(const float4*)(ksqh + ktn + c * 16 + quad * 4);
        mb4n[c] = *(const float4*)(mbb + ktn + c * 16 + quad * 4);
      }
    }
    floatx4 dot[4];
    __builtin_amdgcn_s_setprio(1);
    #pragma unroll
    for (int c = 0; c < 4; c++) {
      const int rbase = (c * 16 + r16) * 64;
      bf16x8 kf0 = *(const bf16x8*)(&lK[cur][rbase + sl0]);
      bf16x8 kf1 = *(const bf16x8*)(&lK[cur][rbase + sl1]);
      floatx4 a = {};
      a = __builtin_amdgcn_mfma_f32_16x16x32_bf16(kf0, qf0, a, 0, 0, 0);
      a = __builtin_amdgcn_mfma_f32_16x16x32_bf16(kf1, qf1, a, 0, 0, 0);
      dot[c] = a;
    }
    __builtin_amdgcn_s_setprio(0);
    float rmax = -1e30f;
    #pragma unroll
    for (int c = 0; c < 4; c++) {
      #pragma unroll
      for (int reg = 0; reg < 4; reg++) {
        const float dd = dot[c][reg];
        const float qks = ((const float*)&ks4[c])[reg];  // qs + kss + eps
        const float mbv = ((const float*)&mb4[c])[reg];
        const float den = __builtin_fmaf(dd, -2.f, qks);
        const float sc = __builtin_fmaf((dd * 1.44269504f) * dd,
                                        __builtin_amdgcn_rcpf(den), mbv);
        dot[c][reg] = sc;
        rmax = fmaxf(rmax, sc);
      }
    }
    if (!__all(rmax <= mi + 11.5416f)) {
      float rg = fmaxf(rmax, __shfl_xor(rmax, 16));
      rg = fmaxf(rg, __shfl_xor(rg, 32));
      const float mnew = fmaxf(mi, rg);
      const float alpha = exp2f(mi - mnew);
      li *= alpha;
      #pragma unroll
      for (int t4 = 0; t4 < 4; t4++) {
        #pragma unroll
        for (int reg = 0; reg < 4; reg++) of[t4][reg] *= alpha;
      }
      mi = mnew;
    }
    float psum = 0.f;
    #pragma unroll
    for (int c = 0; c < 4; c++) {
      bf16x4 pk;
      #pragma unroll
      for (int reg = 0; reg < 4; reg++) {
        const float p = exp2f(dot[c][reg] - mi);  // masked: exp2(-huge)=0
        psum += p;
        pk[reg] = (bf16_t)p;
      }
      const int jw = (2 * c + (quad >> 1)) ^ pswz;
      *(bf16x4*)(myP + r16 * 64 + jw * 8 + (quad & 1) * 4) = pk;
    }
    li += psum;
    bf16x8 pf0 = *(const bf16x8*)(myP + r16 * 64 + (quad ^ pswz) * 8);
    bf16x8 pf1 = *(const bf16x8*)(myP + r16 * 64 + ((4 + quad) ^ pswz) * 8);
    __builtin_amdgcn_s_setprio(1);
    #pragma unroll
    for (int t4 = 0; t4 < 4; t4++) {
      const int rbase = (t4 * 16 + r16) * 64;
      bf16x8 vf0 = *(const bf16x8*)(&lV[cur][rbase + sl0]);
      bf16x8 vf1 = *(const bf16x8*)(&lV[cur][rbase + sl1]);
      of[t4] = __builtin_amdgcn_mfma_f32_16x16x32_bf16(vf0, pf0, of[t4], 0, 0, 0);
      of[t4] = __builtin_amdgcn_mfma_f32_16x16x32_bf16(vf1, pf1, of[t4], 0, 0, 0);
    }
    __builtin_amdgcn_s_setprio(0);
    if (more) {
      #pragma unroll
      for (int c = 0; c < 4; c++) {
        ks4[c] = make_float4(ks4n[c].x + qs, ks4n[c].y + qs,
                             ks4n[c].z + qs, ks4n[c].w + qs);
        mb4[c] = mb4n[c];
      }
    }
    __syncthreads();
  }
  li += __shfl_xor(li, 16);
  li += __shfl_xor(li, 32);
  const float inv = (li > 0.f) ? __builtin_amdgcn_rcpf(li) : 0.f;
  bf16_t* aor = AO + ((size_t)(b * Lc + q0 + r16)) * Ec + h * 64;
  #pragma unroll
  for (int t4 = 0; t4 < 4; t4++) {
    bf16x4 o;
    #pragma unroll
    for (int reg = 0; reg < 4; reg++) o[reg] = (bf16_t)(of[t4][reg] * inv);
    *(bf16x4*)(aor + t4 * 16 + quad * 4) = o;
  }
}

// ---------------- launch ----------------

extern "C" void kernel_launch(void* const* d_in, const int* in_sizes, int n_in,
                              void* d_out, int out_size, void* d_ws, size_t ws_size,
                              hipStream_t stream) {
  const float* x    = (const float*)d_in[0];
  const int*   mask = (const int*)d_in[1];
  const float* Wqkv = (const float*)d_in[2];
  const float* bqkv = (const float*)d_in[3];
  const float* Wout = (const float*)d_in[4];
  const float* bout = (const float*)d_in[5];
  float* out = (float*)d_out;

  auto al = [](size_t x) { return (x + 255) & ~(size_t)255; };
  char* ws = (char*)d_ws;
  size_t off = 0;
  auto carve = [&](size_t bytes) -> char* {
    char* p = ws + off;
    off += al(bytes);
    return p;
  };
  bf16_t* WoT = (bf16_t*)carve((size_t)Ec * Ec * 2);
  bf16_t* Qb  = (bf16_t*)carve((size_t)ROWSc * Dc * 2);
  bf16_t* Kb  = (bf16_t*)carve((size_t)ROWSc * Dc * 2);
  bf16_t* VTb = (bf16_t*)carve((size_t)ROWSc * Dc * 2);
  bf16_t* AOb = (bf16_t*)carve((size_t)Mc * Ec * 2);
  float*  qsq = (float*)carve((size_t)ROWSc * 4);
  float*  ksq = (float*)carve((size_t)ROWSc * 4);
  float*  mbias = (float*)carve((size_t)Bc * Lc * 4);
  const size_t uni = off;
  bf16_t* xb  = (bf16_t*)(ws + uni);
  bf16_t* WqT = (bf16_t*)(ws + uni + al((size_t)Mc * Ec * 2));
  (void)in_sizes; (void)n_in; (void)out_size; (void)ws_size;

  k_prep<<<5392, 256, 0, stream>>>(x, xb, Wqkv, WqT, Wout, WoT, mask, mbias);
  k_gemm_qkv<<<dim3(N3c / 128, Mc / 128), 256, 0, stream>>>(xb, WqT, bqkv, Qb, Kb, VTb, qsq, ksq);
  k_attn<<<dim3(ROWSc / 64), 256, 0, stream>>>(Qb, Kb, VTb, qsq, ksq, mbias, AOb);
  k_gemm_out<<<dim3(Ec / 128, Mc / 128), 256, 0, stream>>>(AOb, WoT, bout, out);
}

// Round 13
// 209.276 us; speedup vs baseline: 1.0523x; 1.0436x over previous
//
#include <hip/hip_runtime.h>
#include <hip/hip_bf16.h>
#include <cstdint>
#include <cstddef>

// YatAttention on MI355X (gfx950).
// B=2, L=2048, E=768, H=12, D=64. GEMMs in bf16 MFMA 16x16x32 (fp32 accum).
// R15: revert to R12, the best verified configuration (211.4us). R13/R14
// attribution: BOTH the GEMM dbuf (+9us) and the qsq/ksq epilogue fusion
// (+7us: 64 shfl_xor in the epilogue beats a 192-block streaming prep2
// kernel... in the wrong direction) were regressions. R12 pipeline:
// k_prep (cvt+W^T), k_gemm_qkv (BK=32 single-buf core, V->VT direct store),
// k_prep2 (192 blocks: sq+eps+mbias), k_attn (R8 structure + lP-64 swizzle
// + setprio + qs-fold, 92-94us pinned), k_gemm_out.

typedef __bf16 bf16_t;
typedef __bf16 bf16x8 __attribute__((ext_vector_type(8)));
typedef __bf16 bf16x4 __attribute__((ext_vector_type(4)));
typedef float floatx4 __attribute__((ext_vector_type(4)));

#define DEVI static __device__ __forceinline__

#define Bc 2
#define Lc 2048
#define Ec 768
#define Hc 12
#define Dc 64
#define N3c 2304
#define Mc 4096
#define ROWSc (Bc * Hc * Lc)  // 49152

DEVI void glds16(const bf16_t* g, bf16_t* l) {
  __builtin_amdgcn_global_load_lds(
      (const __attribute__((address_space(1))) void*)g,
      (__attribute__((address_space(3))) void*)l, 16, 0, 0);
}

// ---------------- fused prep: fp32->bf16 cvt + two weight transposes -------
__global__ __launch_bounds__(256) void k_prep(
    const float* __restrict__ x, bf16_t* __restrict__ xb,
    const float* __restrict__ Wqkv, bf16_t* __restrict__ WqT,
    const float* __restrict__ Wout, bf16_t* __restrict__ WoT) {
  __shared__ float tile[32][33];
  const int bid = blockIdx.x, tid = threadIdx.x;
  if (bid < 3072) {
    const int i = (bid * 256 + tid) * 4;
    float4 v = *(const float4*)(x + i);
    bf16x4 o;
    o[0] = (bf16_t)v.x; o[1] = (bf16_t)v.y; o[2] = (bf16_t)v.z; o[3] = (bf16_t)v.w;
    *(bf16x4*)(xb + i) = o;
    return;
  }
  const float* in; bf16_t* out; int C, local;
  if (bid < 4800) { local = bid - 3072; in = Wqkv; out = WqT; C = N3c; }
  else            { local = bid - 4800; in = Wout; out = WoT; C = Ec;  }
  const int R = Ec;
  const int nbx = C / 32;
  const int c0 = (local % nbx) * 32, r0 = (local / nbx) * 32;
  const int tx = tid & 31, ty = tid >> 5;
  #pragma unroll
  for (int i = 0; i < 32; i += 8)
    tile[ty + i][tx] = in[(size_t)(r0 + ty + i) * C + c0 + tx];
  __syncthreads();
  #pragma unroll
  for (int i = 0; i < 32; i += 8)
    out[(size_t)(c0 + ty + i) * R + r0 + tx] = (bf16_t)tile[tx][ty + i];
}

// ---------------- GEMM core (m97 pattern, BK=32 -- proven) ----------------

DEVI void gemm_core(const bf16_t* __restrict__ A, const bf16_t* __restrict__ Bt,
                    bf16_t* lA, bf16_t* lB, int m0, int n0, floatx4 (&acc)[4][4]) {
  const int tid = threadIdx.x, wave = tid >> 6, lane = tid & 63;
  const int wm = (wave >> 1) * 64, wn = (wave & 1) * 64;
  const int lrow = lane >> 2, lseg = lane & 3;
  const int quad = lane >> 4, r16 = lane & 15;
  for (int kk = 0; kk < 768; kk += 32) {
    glds16(A  + (size_t)(m0 + wave * 32      + lrow) * 768 + kk + lseg * 8, lA + (wave * 32) * 32);
    glds16(A  + (size_t)(m0 + wave * 32 + 16 + lrow) * 768 + kk + lseg * 8, lA + (wave * 32 + 16) * 32);
    glds16(Bt + (size_t)(n0 + wave * 32      + lrow) * 768 + kk + lseg * 8, lB + (wave * 32) * 32);
    glds16(Bt + (size_t)(n0 + wave * 32 + 16 + lrow) * 768 + kk + lseg * 8, lB + (wave * 32 + 16) * 32);
    __syncthreads();
    bf16x8 af[4], bv[4];
    #pragma unroll
    for (int mi = 0; mi < 4; mi++)
      af[mi] = *(const bf16x8*)(lA + (wm + mi * 16 + r16) * 32 + quad * 8);
    #pragma unroll
    for (int ni = 0; ni < 4; ni++)
      bv[ni] = *(const bf16x8*)(lB + (wn + ni * 16 + r16) * 32 + quad * 8);
    #pragma unroll
    for (int mi = 0; mi < 4; mi++)
      #pragma unroll
      for (int ni = 0; ni < 4; ni++)
        acc[mi][ni] = __builtin_amdgcn_mfma_f32_16x16x32_bf16(af[mi], bv[ni], acc[mi][ni], 0, 0, 0);
    __syncthreads();
  }
}

// QKV GEMM; V section (sec==2) writes VT[bh][d][l] directly (bf16x4, 8B
// contiguous along l) -- the V transpose is free here.
__global__ __launch_bounds__(256) void k_gemm_qkv(
    const bf16_t* __restrict__ A, const bf16_t* __restrict__ Bt,
    const float* __restrict__ bias,
    bf16_t* __restrict__ Qo, bf16_t* __restrict__ Ko, bf16_t* __restrict__ VTo) {
  __shared__ bf16_t lA[128 * 32];
  __shared__ bf16_t lB[128 * 32];
  const int m0 = blockIdx.y * 128, n0 = blockIdx.x * 128;
  const int tid = threadIdx.x, wave = tid >> 6, lane = tid & 63;
  const int wm = (wave >> 1) * 64, wn = (wave & 1) * 64;
  const int quad = lane >> 4, r16 = lane & 15;
  floatx4 acc[4][4] = {};
  gemm_core(A, Bt, lA, lB, m0, n0, acc);

  const int sec = n0 / 768;
  if (sec < 2) {
    bf16_t* dst = (sec == 0) ? Qo : Ko;
    #pragma unroll
    for (int ni = 0; ni < 4; ni++) {
      const int n = n0 + wn + ni * 16 + r16;
      const int nn = n - sec * 768;
      const int h = nn >> 6, d = nn & 63;
      const float bvs = bias[n];
      #pragma unroll
      for (int mi = 0; mi < 4; mi++) {
        #pragma unroll
        for (int reg = 0; reg < 4; reg++) {
          const int m = m0 + wm + mi * 16 + quad * 4 + reg;
          const int b = m >> 11, l = m & 2047;
          const float v = acc[mi][ni][reg] + bvs;
          dst[(((size_t)(b * Hc + h)) * Lc + l) * Dc + d] = (bf16_t)v;
        }
      }
    }
  } else {
    // V -> VT direct: lane owns fixed (h,d); regs are 4 consecutive l.
    #pragma unroll
    for (int ni = 0; ni < 4; ni++) {
      const int n = n0 + wn + ni * 16 + r16;
      const int nn = n - 1536;
      const int h = nn >> 6, d = nn & 63;
      const float bvs = bias[n];
      #pragma unroll
      for (int mi = 0; mi < 4; mi++) {
        const int m = m0 + wm + mi * 16 + quad * 4;
        const int b = m >> 11, l = m & 2047;
        bf16x4 o;
        #pragma unroll
        for (int reg = 0; reg < 4; reg++)
          o[reg] = (bf16_t)(acc[mi][ni][reg] + bvs);
        *(bf16x4*)(VTo + (((size_t)(b * Hc + h)) * Dc + d) * Lc + l) = o;
      }
    }
  }
}

__global__ __launch_bounds__(256) void k_gemm_out(
    const bf16_t* __restrict__ A, const bf16_t* __restrict__ Bt,
    const float* __restrict__ bias, float* __restrict__ out) {
  __shared__ bf16_t lA[128 * 32];
  __shared__ bf16_t lB[128 * 32];
  const int m0 = blockIdx.y * 128, n0 = blockIdx.x * 128;
  const int tid = threadIdx.x, wave = tid >> 6, lane = tid & 63;
  const int wm = (wave >> 1) * 64, wn = (wave & 1) * 64;
  const int quad = lane >> 4, r16 = lane & 15;
  floatx4 acc[4][4] = {};
  gemm_core(A, Bt, lA, lB, m0, n0, acc);
  #pragma unroll
  for (int ni = 0; ni < 4; ni++) {
    const int n = n0 + wn + ni * 16 + r16;
    const float bvs = bias[n];
    #pragma unroll
    for (int mi = 0; mi < 4; mi++) {
      #pragma unroll
      for (int reg = 0; reg < 4; reg++) {
        const int m = m0 + wm + mi * 16 + quad * 4 + reg;
        out[(size_t)m * Ec + n] = acc[mi][ni][reg] + bvs;
      }
    }
  }
}

// ------- prep2: q_sq/k_sq (+eps) + mask bias (sq-only; grid 192) -------
__global__ __launch_bounds__(256) void k_prep2(
    const bf16_t* __restrict__ Q, const bf16_t* __restrict__ K,
    const int* __restrict__ mask,
    float* __restrict__ qsq, float* __restrict__ ksq,
    float* __restrict__ mbias) {
  const int row = blockIdx.x * 256 + threadIdx.x;
  const bf16x8* q = (const bf16x8*)(Q + (size_t)row * 64);
  const bf16x8* k = (const bf16x8*)(K + (size_t)row * 64);
  float sq = 0.f, sk = 0.f;
  #pragma unroll
  for (int c = 0; c < 8; c++) {
    bf16x8 vq = q[c], vk = k[c];
    #pragma unroll
    for (int j = 0; j < 8; j++) {
      float a = (float)vq[j]; sq += a * a;
      float b = (float)vk[j]; sk += b * b;
    }
  }
  qsq[row] = sq;
  ksq[row] = sk + 1e-6f;
  const int bh = row >> 11, l = row & 2047;
  if (bh == 0 || bh == Hc) {
    const int b = bh / Hc;
    mbias[b * Lc + l] = (mask[b * Lc + l] == 1) ? 0.f : -1e30f;
  }
}

// ---------------- flash attention: R8 structure + lP-64 swizzle + setprio --
// grid = 768. Block: 4 waves, 64 queries (wave = 16). Key tile = 64.
// K+V glds16 dbuf (proven); lP stride-64 + 16B-chunk XOR swizzle; S^T =
// K.Q^T; O^T = VT.P^T; softmax per-lane (query = r16), log2 domain, gated
// defer-rescale, li per-lane partial. qs folded into ks4 at prefetch time.
__global__ __launch_bounds__(256) void k_attn(
    const bf16_t* __restrict__ Q, const bf16_t* __restrict__ K,
    const bf16_t* __restrict__ VT, const float* __restrict__ qsq,
    const float* __restrict__ ksq, const float* __restrict__ mbias,
    bf16_t* __restrict__ AO) {
  __shared__ bf16_t lK[2][4096];    // 64 keys x 64 d, swizzled 16B chunks
  __shared__ bf16_t lV[2][4096];    // 64 d x 64 keys, swizzled 16B chunks
  __shared__ bf16_t lP[4][16 * 64]; // per-wave P, stride 64, chunk-XOR swizzle
  const int gid0 = blockIdx.x;
  const int gid = (gid0 & 7) * 96 + (gid0 >> 3);  // XCD swizzle: 3 bh per XCD
  const int bh = gid >> 5, qt = gid & 31;
  const int b = bh / Hc;
  const int h = bh - b * Hc;
  const int tid = threadIdx.x, wave = tid >> 6, lane = tid & 63;
  const int quad = lane >> 4, r16 = lane & 15;
  const int q0 = qt * 64 + wave * 16;
  const bf16_t* Qh = Q + ((size_t)bh * Lc) * Dc;
  const bf16_t* Kh = K + ((size_t)bh * Lc) * Dc;
  const bf16_t* VTh = VT + ((size_t)bh * Dc) * Lc;
  const float* qsqh = qsq + bh * Lc;
  const float* ksqh = ksq + bh * Lc;
  const float* mbb = mbias + b * Lc;
  bf16_t* myP = &lP[wave][0];

  const int p0 = wave * 64 + lane;
  const int srow = p0 >> 3;
  const int sj = (p0 & 7) ^ (srow & 7);
  const bf16_t* kg0 = Kh + (size_t)srow * 64 + sj * 8;
  const bf16_t* kg1 = kg0 + 32 * 64;
  const bf16_t* vg0 = VTh + (size_t)srow * Lc + sj * 8;
  const bf16_t* vg1 = vg0 + 32 * Lc;
  const int ld0 = wave * 64 * 8, ld1 = (256 + wave * 64) * 8;  // elements

  const int sl0 = ((quad ^ (r16 & 7)) * 8);
  const int sl1 = sl0 ^ 32;
  const int pswz = r16 & 7;

  bf16x8 qf0 = *(const bf16x8*)(Qh + (size_t)(q0 + r16) * 64 + quad * 8);
  bf16x8 qf1 = *(const bf16x8*)(Qh + (size_t)(q0 + r16) * 64 + 32 + quad * 8);
  const float qs = qsqh[q0 + r16];
  float mi = -1e30f;        // LOG2 domain, shared across the query's 4 lanes
  float li = 0.f;           // per-lane partial; reduced in epilogue
  floatx4 of[4] = {};

  glds16(kg0, &lK[0][ld0]);
  glds16(kg1, &lK[0][ld1]);
  glds16(vg0, &lV[0][ld0]);
  glds16(vg1, &lV[0][ld1]);
  kg0 += 4096; kg1 += 4096; vg0 += 64; vg1 += 64;
  float4 ks4[4], mb4[4];
  #pragma unroll
  for (int c = 0; c < 4; c++) {
    float4 kv = *(const float4*)(ksqh + c * 16 + quad * 4);
    ks4[c] = make_float4(kv.x + qs, kv.y + qs, kv.z + qs, kv.w + qs);
    mb4[c] = *(const float4*)(mbb + c * 16 + quad * 4);
  }
  __syncthreads();

  const int nt = Lc / 64;  // 32
  for (int t = 0; t < nt; t++) {
    const int cur = t & 1;
    const bool more = (t + 1 < nt);
    if (more) {
      const int nxt = cur ^ 1;
      glds16(kg0, &lK[nxt][ld0]);
      glds16(kg1, &lK[nxt][ld1]);
      glds16(vg0, &lV[nxt][ld0]);
      glds16(vg1, &lV[nxt][ld1]);
      kg0 += 4096; kg1 += 4096; vg0 += 64; vg1 += 64;
    }
    float4 ks4n[4], mb4n[4];
    if (more) {
      const int ktn = (t + 1) * 64;
      #pragma unroll
      for (int c = 0; c < 4; c++) {
        ks4n[c] = *(const float4*)(ksqh + ktn + c * 16 + quad * 4);
        mb4n[c] = *(const float4*)(mbb + ktn + c * 16 + quad * 4);
      }
    }
    floatx4 dot[4];
    __builtin_amdgcn_s_setprio(1);
    #pragma unroll
    for (int c = 0; c < 4; c++) {
      const int rbase = (c * 16 + r16) * 64;
      bf16x8 kf0 = *(const bf16x8*)(&lK[cur][rbase + sl0]);
      bf16x8 kf1 = *(const bf16x8*)(&lK[cur][rbase + sl1]);
      floatx4 a = {};
      a = __builtin_amdgcn_mfma_f32_16x16x32_bf16(kf0, qf0, a, 0, 0, 0);
      a = __builtin_amdgcn_mfma_f32_16x16x32_bf16(kf1, qf1, a, 0, 0, 0);
      dot[c] = a;
    }
    __builtin_amdgcn_s_setprio(0);
    float rmax = -1e30f;
    #pragma unroll
    for (int c = 0; c < 4; c++) {
      #pragma unroll
      for (int reg = 0; reg < 4; reg++) {
        const float dd = dot[c][reg];
        const float qks = ((const float*)&ks4[c])[reg];  // qs + kss + eps
        const float mbv = ((const float*)&mb4[c])[reg];
        const float den = __builtin_fmaf(dd, -2.f, qks);
        const float sc = __builtin_fmaf((dd * 1.44269504f) * dd,
                                        __builtin_amdgcn_rcpf(den), mbv);
        dot[c][reg] = sc;
        rmax = fmaxf(rmax, sc);
      }
    }
    if (!__all(rmax <= mi + 11.5416f)) {
      float rg = fmaxf(rmax, __shfl_xor(rmax, 16));
      rg = fmaxf(rg, __shfl_xor(rg, 32));
      const float mnew = fmaxf(mi, rg);
      const float alpha = exp2f(mi - mnew);
      li *= alpha;
      #pragma unroll
      for (int t4 = 0; t4 < 4; t4++) {
        #pragma unroll
        for (int reg = 0; reg < 4; reg++) of[t4][reg] *= alpha;
      }
      mi = mnew;
    }
    float psum = 0.f;
    #pragma unroll
    for (int c = 0; c < 4; c++) {
      bf16x4 pk;
      #pragma unroll
      for (int reg = 0; reg < 4; reg++) {
        const float p = exp2f(dot[c][reg] - mi);  // masked: exp2(-huge)=0
        psum += p;
        pk[reg] = (bf16_t)p;
      }
      const int jw = (2 * c + (quad >> 1)) ^ pswz;
      *(bf16x4*)(myP + r16 * 64 + jw * 8 + (quad & 1) * 4) = pk;
    }
    li += psum;
    bf16x8 pf0 = *(const bf16x8*)(myP + r16 * 64 + (quad ^ pswz) * 8);
    bf16x8 pf1 = *(const bf16x8*)(myP + r16 * 64 + ((4 + quad) ^ pswz) * 8);
    __builtin_amdgcn_s_setprio(1);
    #pragma unroll
    for (int t4 = 0; t4 < 4; t4++) {
      const int rbase = (t4 * 16 + r16) * 64;
      bf16x8 vf0 = *(const bf16x8*)(&lV[cur][rbase + sl0]);
      bf16x8 vf1 = *(const bf16x8*)(&lV[cur][rbase + sl1]);
      of[t4] = __builtin_amdgcn_mfma_f32_16x16x32_bf16(vf0, pf0, of[t4], 0, 0, 0);
      of[t4] = __builtin_amdgcn_mfma_f32_16x16x32_bf16(vf1, pf1, of[t4], 0, 0, 0);
    }
    __builtin_amdgcn_s_setprio(0);
    if (more) {
      #pragma unroll
      for (int c = 0; c < 4; c++) {
        ks4[c] = make_float4(ks4n[c].x + qs, ks4n[c].y + qs,
                             ks4n[c].z + qs, ks4n[c].w + qs);
        mb4[c] = mb4n[c];
      }
    }
    __syncthreads();
  }
  li += __shfl_xor(li, 16);
  li += __shfl_xor(li, 32);
  const float inv = (li > 0.f) ? __builtin_amdgcn_rcpf(li) : 0.f;
  bf16_t* aor = AO + ((size_t)(b * Lc + q0 + r16)) * Ec + h * 64;
  #pragma unroll
  for (int t4 = 0; t4 < 4; t4++) {
    bf16x4 o;
    #pragma unroll
    for (int reg = 0; reg < 4; reg++) o[reg] = (bf16_t)(of[t4][reg] * inv);
    *(bf16x4*)(aor + t4 * 16 + quad * 4) = o;
  }
}

// ---------------- launch ----------------

extern "C" void kernel_launch(void* const* d_in, const int* in_sizes, int n_in,
                              void* d_out, int out_size, void* d_ws, size_t ws_size,
                              hipStream_t stream) {
  const float* x    = (const float*)d_in[0];
  const int*   mask = (const int*)d_in[1];
  const float* Wqkv = (const float*)d_in[2];
  const float* bqkv = (const float*)d_in[3];
  const float* Wout = (const float*)d_in[4];
  const float* bout = (const float*)d_in[5];
  float* out = (float*)d_out;

  auto al = [](size_t x) { return (x + 255) & ~(size_t)255; };
  char* ws = (char*)d_ws;
  size_t off = 0;
  auto carve = [&](size_t bytes) -> char* {
    char* p = ws + off;
    off += al(bytes);
    return p;
  };
  bf16_t* WoT = (bf16_t*)carve((size_t)Ec * Ec * 2);
  bf16_t* Qb  = (bf16_t*)carve((size_t)ROWSc * Dc * 2);
  bf16_t* Kb  = (bf16_t*)carve((size_t)ROWSc * Dc * 2);
  bf16_t* VTb = (bf16_t*)carve((size_t)ROWSc * Dc * 2);
  bf16_t* AOb = (bf16_t*)carve((size_t)Mc * Ec * 2);
  float*  qsq = (float*)carve((size_t)ROWSc * 4);
  float*  ksq = (float*)carve((size_t)ROWSc * 4);
  float*  mbias = (float*)carve((size_t)Bc * Lc * 4);
  const size_t uni = off;
  bf16_t* xb  = (bf16_t*)(ws + uni);
  bf16_t* WqT = (bf16_t*)(ws + uni + al((size_t)Mc * Ec * 2));
  (void)in_sizes; (void)n_in; (void)out_size; (void)ws_size;

  k_prep<<<5376, 256, 0, stream>>>(x, xb, Wqkv, WqT, Wout, WoT);
  k_gemm_qkv<<<dim3(N3c / 128, Mc / 128), 256, 0, stream>>>(xb, WqT, bqkv, Qb, Kb, VTb);
  k_prep2<<<192, 256, 0, stream>>>(Qb, Kb, mask, qsq, ksq, mbias);
  k_attn<<<dim3(ROWSc / 64), 256, 0, stream>>>(Qb, Kb, VTb, qsq, ksq, mbias, AOb);
  k_gemm_out<<<dim3(Ec / 128, Mc / 128), 256, 0, stream>>>(AOb, WoT, bout, out);
}